// Round 4
// baseline (159.390 us; speedup 1.0000x reference)
//
#include <hip/hip_runtime.h>
#include <stdint.h>

#define BB 64
#define NN 2048
#define DD 128
#define ROWS 64           // neighbor rows per chunk
#define CPB 2             // chunks per main block -> grid = 64*16 = 1024

typedef __attribute__((ext_vector_type(8))) short short8;
typedef __attribute__((ext_vector_type(4))) float f32x4;

__device__ __forceinline__ unsigned short f2bf_rtne(float x) {
    union { float f; unsigned int u; } v; v.f = x;
    unsigned int r = v.u + 0x7fffu + ((v.u >> 16) & 1u);
    return (unsigned short)(r >> 16);
}
__device__ __forceinline__ float bf2f(unsigned short h) {
    union { unsigned int u; float f; } v; v.u = ((unsigned int)h) << 16;
    return v.f;
}
__device__ __forceinline__ float tanh_fast(float x) {
    float ax = fabsf(x);
    float e  = __expf(-2.f * ax);
    float t  = (1.f - e) / (1.f + e);
    return copysignf(t, x);
}

// ---- prep: blocks 0..7 convert Wk -> bf16 hi/lo MFMA B-fragments;
//      blocks 8..71: q[b] = e_i[b] @ Wq.T, and zero sprime/denom ----
__global__ __launch_bounds__(256) void aegis_prep(
    const float* __restrict__ e_i, const float* __restrict__ Wq,
    const float* __restrict__ Wk,
    float* __restrict__ qbuf, unsigned short* __restrict__ Bhig,
    unsigned short* __restrict__ Blog,
    float* __restrict__ sprime, float* __restrict__ denom)
{
    __shared__ float eis[DD];
    const int t = threadIdx.x, blk = blockIdx.x;
    if (blk < 8) {
        // fragidx = ((etile*4+ks)*4+lg)*16+lr ; e=etile*16+lr ; k=ks*32+lg*8
        const int tid = blk * 256 + t;
        const int lr = tid & 15, lg = (tid >> 4) & 3, ks = (tid >> 6) & 3, et = tid >> 8;
        const int e = et * 16 + lr, k = ks * 32 + lg * 8;
        const float* src = Wk + e * DD + k;
        float4 x0 = *reinterpret_cast<const float4*>(src);
        float4 x1 = *reinterpret_cast<const float4*>(src + 4);
        float xs[8] = {x0.x, x0.y, x0.z, x0.w, x1.x, x1.y, x1.z, x1.w};
        short8 h, l;
        #pragma unroll
        for (int j = 0; j < 8; ++j) {
            unsigned short hb = f2bf_rtne(xs[j]);
            float rem = xs[j] - bf2f(hb);
            h[j] = (short)hb;
            l[j] = (short)f2bf_rtne(rem);
        }
        *reinterpret_cast<short8*>(Bhig + (size_t)tid * 8) = h;
        *reinterpret_cast<short8*>(Blog + (size_t)tid * 8) = l;
    } else {
        const int b = blk - 8;
        if (t < DD) eis[t] = e_i[b * DD + t];
        __syncthreads();
        if (t < DD) {
            float acc = 0.f;
            const float4* wr = reinterpret_cast<const float4*>(Wq + t * DD);
            const float4* ev = reinterpret_cast<const float4*>(eis);
            #pragma unroll 8
            for (int i = 0; i < 32; ++i) {
                float4 w = wr[i], e = ev[i];
                acc = fmaf(w.x, e.x, acc); acc = fmaf(w.y, e.y, acc);
                acc = fmaf(w.z, e.z, acc); acc = fmaf(w.w, e.w, acc);
            }
            qbuf[b * DD + t] = acc;
            sprime[b * DD + t] = 0.f;
        }
        if (t == 0) denom[b] = 0.f;
    }
}

// ---- main: MFMA K-GEMM (bf16 3-term split) + sigma + exp + weighted colsum ----
__global__ __launch_bounds__(256, 4) void aegis_main(
    const float* __restrict__ e_j, const float* __restrict__ imp,
    const float* __restrict__ omega, const float* __restrict__ qbuf,
    const unsigned short* __restrict__ Bhig, const unsigned short* __restrict__ Blog,
    float* __restrict__ sprime, float* __restrict__ denom)
{
    __shared__ unsigned short Ehi[ROWS * DD];   // XOR-swizzled: byte ^= (row&7)<<4
    __shared__ unsigned short Elo[ROWS * DD];
    __shared__ float sig[ROWS][4];
    __shared__ float wrow[ROWS];
    __shared__ float scol[DD];

    const int t    = threadIdx.x;
    const int b    = blockIdx.x >> 4;
    const int cb   = blockIdx.x & 15;
    const int lane = t & 63;
    const int w    = t >> 6;
    const int lr   = lane & 15;
    const int lg   = lane >> 4;

    // ---- B fragments: coalesced short8 loads from prepped buffers ----
    short8 Bh[2][4], Bl[2][4];
    #pragma unroll
    for (int ct = 0; ct < 2; ++ct)
        #pragma unroll
        for (int ks = 0; ks < 4; ++ks) {
            const int fi = (((2 * w + ct) * 4 + ks) * 4 + lg) * 16 + lr;
            Bh[ct][ks] = *reinterpret_cast<const short8*>(Bhig + (size_t)fi * 8);
            Bl[ct][ks] = *reinterpret_cast<const short8*>(Blog + (size_t)fi * 8);
        }

    float qv[2], ov[2];
    #pragma unroll
    for (int ct = 0; ct < 2; ++ct) {
        const int c = 32 * w + 16 * ct + lr;
        qv[ct] = qbuf[b * DD + c];
        ov[ct] = omega[c];
    }

    const int d  = t & 127;
    const int hf = t >> 7;
    float sacc = 0.f, den_local = 0.f;

    #pragma unroll 1
    for (int c = 0; c < CPB; ++c) {
        const int row0 = (cb * CPB + c) * ROWS;
        __syncthreads();   // protect E from previous chunk's colsum readers

        // ---- stage 64 rows as bf16 hi/lo, XOR-swizzled ----
        {
            const float4* src = reinterpret_cast<const float4*>(
                e_j + ((size_t)(b * NN + row0)) * DD);
            #pragma unroll
            for (int i = 0; i < 8; ++i) {
                const int idx = t + i * 256;       // 2048 float4 slots
                const int rr  = idx >> 5;
                const int bc  = (idx & 31) * 8;    // byte col within 256B row
                float4 v = src[idx];
                float xs[4] = {v.x, v.y, v.z, v.w};
                unsigned short hs[4], ls[4];
                #pragma unroll
                for (int j = 0; j < 4; ++j) {
                    hs[j] = f2bf_rtne(xs[j]);
                    ls[j] = f2bf_rtne(xs[j] - bf2f(hs[j]));
                }
                uint2 ph, pl;
                ph.x = (unsigned)hs[0] | ((unsigned)hs[1] << 16);
                ph.y = (unsigned)hs[2] | ((unsigned)hs[3] << 16);
                pl.x = (unsigned)ls[0] | ((unsigned)ls[1] << 16);
                pl.y = (unsigned)ls[2] | ((unsigned)ls[3] << 16);
                const int off = rr * 256 + (bc ^ ((rr & 7) << 4));
                *reinterpret_cast<uint2*>(reinterpret_cast<char*>(Ehi) + off) = ph;
                *reinterpret_cast<uint2*>(reinterpret_cast<char*>(Elo) + off) = pl;
            }
        }
        __syncthreads();

        // ---- MFMA K-GEMM + sigma partials ----
        #pragma unroll 1
        for (int rt = 0; rt < 4; ++rt) {
            f32x4 a0 = {0.f, 0.f, 0.f, 0.f};
            f32x4 a1 = {0.f, 0.f, 0.f, 0.f};
            const int arow = rt * 16 + lr;
            const int rbase = arow * 256;
            const int rsw   = (lr & 7) << 4;
            #pragma unroll
            for (int ks = 0; ks < 4; ++ks) {
                const int off = rbase + ((ks * 64 + lg * 16) ^ rsw);
                short8 ah = *reinterpret_cast<const short8*>(
                    reinterpret_cast<const char*>(Ehi) + off);
                short8 al = *reinterpret_cast<const short8*>(
                    reinterpret_cast<const char*>(Elo) + off);
                a0 = __builtin_amdgcn_mfma_f32_16x16x32_bf16(ah, Bh[0][ks], a0, 0, 0, 0);
                a1 = __builtin_amdgcn_mfma_f32_16x16x32_bf16(ah, Bh[1][ks], a1, 0, 0, 0);
                a0 = __builtin_amdgcn_mfma_f32_16x16x32_bf16(ah, Bl[0][ks], a0, 0, 0, 0);
                a1 = __builtin_amdgcn_mfma_f32_16x16x32_bf16(ah, Bl[1][ks], a1, 0, 0, 0);
                a0 = __builtin_amdgcn_mfma_f32_16x16x32_bf16(al, Bh[0][ks], a0, 0, 0, 0);
                a1 = __builtin_amdgcn_mfma_f32_16x16x32_bf16(al, Bh[1][ks], a1, 0, 0, 0);
            }
            float sp[4];
            #pragma unroll
            for (int i = 0; i < 4; ++i) {
                float x0 = qv[0] + a0[i];
                float x1 = qv[1] + a1[i];
                sp[i] = fmaf(ov[0], tanh_fast(x0), ov[1] * tanh_fast(x1));
            }
            #pragma unroll
            for (int m = 1; m < 16; m <<= 1) {
                #pragma unroll
                for (int i = 0; i < 4; ++i) sp[i] += __shfl_xor(sp[i], m);
            }
            if (lr == 0) {
                #pragma unroll
                for (int i = 0; i < 4; ++i) sig[rt * 16 + 4 * lg + i][w] = sp[i];
            }
        }
        __syncthreads();

        // ---- exp + weights + denominator (wave 0) ----
        if (t < ROWS) {
            float sg = sig[t][0] + sig[t][1] + sig[t][2] + sig[t][3];
            float es = __expf(sg);
            wrow[t]  = es * imp[b * NN + row0 + t];
            float ds = es;
            #pragma unroll
            for (int m = 1; m < 64; m <<= 1) ds += __shfl_xor(ds, m);
            if (t == 0) den_local += ds;
        }
        __syncthreads();

        // ---- weighted column sum ----
        {
            float part = 0.f;
            #pragma unroll
            for (int rr = hf * 32; rr < hf * 32 + 32; ++rr) {
                const int off = rr * 256 + ((2 * d) ^ ((rr & 7) << 4));
                float ev = bf2f(*reinterpret_cast<const unsigned short*>(
                               reinterpret_cast<const char*>(Ehi) + off))
                         + bf2f(*reinterpret_cast<const unsigned short*>(
                               reinterpret_cast<const char*>(Elo) + off));
                part = fmaf(wrow[rr], ev, part);
            }
            sacc += part;
        }
    }

    if (hf == 0) scol[d] = sacc;
    __syncthreads();
    if (hf == 1) atomicAdd(&sprime[b * DD + d], sacc + scol[d]);
    if (t == 0) atomicAdd(&denom[b], den_local);
}

// ---- fused epilogue: A_l = (s'/denom) @ Wv.T ; outputs 0,2 ; A_lk = R * A_l ----
__global__ __launch_bounds__(256) void aegis_epi(
    const float* __restrict__ sprime, const float* __restrict__ denomv,
    const float* __restrict__ Wv, const float* __restrict__ R,
    float* __restrict__ out)
{
    __shared__ float sn[DD];
    __shared__ float alred[DD][2];
    __shared__ float al[DD];
    const int t = threadIdx.x, b = blockIdx.x;

    if (t < DD) sn[t] = sprime[b * DD + t] / (denomv[b] + 1e-9f);
    __syncthreads();
    {
        const int l = t >> 1, h = t & 1;
        const float4* wr = reinterpret_cast<const float4*>(Wv + l * DD + h * 64);
        const float4* sv = reinterpret_cast<const float4*>(sn + h * 64);
        float acc = 0.f;
        #pragma unroll 8
        for (int i = 0; i < 16; ++i) {
            float4 w = wr[i], e = sv[i];
            acc = fmaf(w.x, e.x, acc); acc = fmaf(w.y, e.y, acc);
            acc = fmaf(w.z, e.z, acc); acc = fmaf(w.w, e.w, acc);
        }
        alred[l][h] = acc;
    }
    __syncthreads();
    if (t < DD) {
        float v = alred[t][0] + alred[t][1];
        al[t] = v;
        out[b * DD + t] = v;                       // A_l
        out[8192 + 1048576 + b * DD + t] = v;      // A_l (output 2)
    }
    __syncthreads();
    float4* dst = reinterpret_cast<float4*>(out + 8192 + (size_t)b * DD * DD);
    const float4* rsrc = reinterpret_cast<const float4*>(R);
    #pragma unroll
    for (int i = 0; i < 16; ++i) {
        const int idx = t + i * 256;               // 4096 float4 per b
        float4 r = rsrc[idx];
        const int k0 = (idx & 31) * 4;
        float4 o;
        o.x = r.x * al[k0];     o.y = r.y * al[k0 + 1];
        o.z = r.z * al[k0 + 2]; o.w = r.w * al[k0 + 3];
        dst[idx] = o;
    }
}

extern "C" void kernel_launch(void* const* d_in, const int* in_sizes, int n_in,
                              void* d_out, int out_size, void* d_ws, size_t ws_size,
                              hipStream_t stream) {
    const float* e_i = (const float*)d_in[0];
    const float* e_j = (const float*)d_in[1];
    const float* imp = (const float*)d_in[2];
    const float* R   = (const float*)d_in[3];
    const float* Wq  = (const float*)d_in[4];
    const float* Wk  = (const float*)d_in[5];
    const float* Wv  = (const float*)d_in[6];
    const float* om  = (const float*)d_in[7];

    float* out    = (float*)d_out;
    float* sprime = (float*)d_ws;                        // 8192 f32
    float* denom  = (float*)((char*)d_ws + 32768);       // 64 f32

    // scratch hosted in the A_lk output region (rewritten by epi afterwards):
    float* qbuf = out + 8192;                            // 8192 f32
    unsigned short* Bhig = (unsigned short*)(out + 8192 + 8192);   // 16384 shorts
    unsigned short* Blog = Bhig + 16384;                 // 16384 shorts

    aegis_prep<<<dim3(72), dim3(256), 0, stream>>>(
        e_i, Wq, Wk, qbuf, Bhig, Blog, sprime, denom);
    aegis_main<<<dim3(BB * 16), dim3(256), 0, stream>>>(
        e_j, imp, om, qbuf, Bhig, Blog, sprime, denom);
    aegis_epi<<<dim3(BB), dim3(256), 0, stream>>>(sprime, denom, Wv, R, out);
}

// Round 6
// 153.334 us; speedup vs baseline: 1.0395x; 1.0395x over previous
//
#include <hip/hip_runtime.h>
#include <stdint.h>

#define BB 64
#define NN 2048
#define DD 128
#define ROWS 64           // neighbor rows per chunk
#define CPB 2             // chunks per block -> grid = 64*16 = 1024

typedef __attribute__((ext_vector_type(8))) short short8;
typedef __attribute__((ext_vector_type(4))) float f32x4;

__device__ __forceinline__ unsigned short f2bf_rtne(float x) {
    union { float f; unsigned int u; } v; v.f = x;
    unsigned int r = v.u + 0x7fffu + ((v.u >> 16) & 1u);
    return (unsigned short)(r >> 16);
}
__device__ __forceinline__ float bf2f(unsigned short h) {
    union { unsigned int u; float f; } v; v.u = ((unsigned int)h) << 16;
    return v.f;
}
__device__ __forceinline__ float tanh_fast(float x) {
    float ax = fabsf(x);
    float e  = __expf(-2.f * ax);
    float t  = (1.f - e) / (1.f + e);
    return copysignf(t, x);
}
// Raw barrier: LDS-publish only. Leaves global loads (vmcnt) in flight,
// unlike __syncthreads() which drains vmcnt(0) and kills prefetch overlap.
__device__ __forceinline__ void ldsbar() {
    asm volatile("s_waitcnt lgkmcnt(0)" ::: "memory");
    __builtin_amdgcn_s_barrier();
}

// ---- prep: blocks 0..7 convert Wk -> bf16 hi/lo MFMA B-fragments;
//      blocks 8..71: q[b] = e_i[b] @ Wq.T, zero sprime/denom ----
__global__ __launch_bounds__(256) void aegis_prep(
    const float* __restrict__ e_i, const float* __restrict__ Wq,
    const float* __restrict__ Wk,
    float* __restrict__ qbuf, unsigned short* __restrict__ Bhig,
    unsigned short* __restrict__ Blog,
    float* __restrict__ sprime, float* __restrict__ denom)
{
    __shared__ float eis[DD];
    const int t = threadIdx.x, blk = blockIdx.x;
    if (blk < 8) {
        const int tid = blk * 256 + t;
        const int lr = tid & 15, lg = (tid >> 4) & 3, ks = (tid >> 6) & 3, et = tid >> 8;
        const int e = et * 16 + lr, k = ks * 32 + lg * 8;
        const float* src = Wk + e * DD + k;
        float4 x0 = *reinterpret_cast<const float4*>(src);
        float4 x1 = *reinterpret_cast<const float4*>(src + 4);
        float xs[8] = {x0.x, x0.y, x0.z, x0.w, x1.x, x1.y, x1.z, x1.w};
        short8 h, l;
        #pragma unroll
        for (int j = 0; j < 8; ++j) {
            unsigned short hb = f2bf_rtne(xs[j]);
            float rem = xs[j] - bf2f(hb);
            h[j] = (short)hb;
            l[j] = (short)f2bf_rtne(rem);
        }
        *reinterpret_cast<short8*>(Bhig + (size_t)tid * 8) = h;
        *reinterpret_cast<short8*>(Blog + (size_t)tid * 8) = l;
    } else {
        const int b = blk - 8;
        if (t < DD) eis[t] = e_i[b * DD + t];
        __syncthreads();
        if (t < DD) {
            float acc = 0.f;
            const float4* wr = reinterpret_cast<const float4*>(Wq + t * DD);
            const float4* ev = reinterpret_cast<const float4*>(eis);
            #pragma unroll 8
            for (int i = 0; i < 32; ++i) {
                float4 w = wr[i], e = ev[i];
                acc = fmaf(w.x, e.x, acc); acc = fmaf(w.y, e.y, acc);
                acc = fmaf(w.z, e.z, acc); acc = fmaf(w.w, e.w, acc);
            }
            qbuf[b * DD + t] = acc;
            sprime[b * DD + t] = 0.f;
        }
        if (t == 0) denom[b] = 0.f;
    }
}

// ---- main: pipelined MFMA K-GEMM + sigma + exp + weighted colsum ----
__global__ __launch_bounds__(256, 3) void aegis_main(
    const float* __restrict__ e_j, const float* __restrict__ imp,
    const float* __restrict__ omega, const float* __restrict__ qbuf,
    const unsigned short* __restrict__ Bhig, const unsigned short* __restrict__ Blog,
    float* __restrict__ sprime, float* __restrict__ denom)
{
    __shared__ unsigned short Ehi[ROWS * DD];   // byte off = rr*256 + (col_bytes ^ ((rr&7)<<4))
    __shared__ unsigned short Elo[ROWS * DD];
    __shared__ float sig[ROWS][4];
    __shared__ float wrow[ROWS];
    __shared__ float scolq[4][DD];

    const int t    = threadIdx.x;
    const int b    = blockIdx.x >> 4;
    const int cb   = blockIdx.x & 15;
    const int lane = t & 63;
    const int w    = t >> 6;
    const int lr   = lane & 15;
    const int lg   = lane >> 4;
    const int row0 = cb * (CPB * ROWS);

    // ---- issue chunk-0 e_j loads FIRST (oldest vmcnt slots) ----
    float4 st[8];
    const float4* ejp = reinterpret_cast<const float4*>(
        e_j + (size_t)(b * NN + row0) * DD);
    #pragma unroll
    for (int i = 0; i < 8; ++i) st[i] = ejp[t + i * 256];

    // ---- B fragments (stay in flight until first MFMA) ----
    short8 Bh[2][4], Bl[2][4];
    #pragma unroll
    for (int ct = 0; ct < 2; ++ct)
        #pragma unroll
        for (int ks = 0; ks < 4; ++ks) {
            const int fi = (((2 * w + ct) * 4 + ks) * 4 + lg) * 16 + lr;
            Bh[ct][ks] = *reinterpret_cast<const short8*>(Bhig + (size_t)fi * 8);
            Bl[ct][ks] = *reinterpret_cast<const short8*>(Blog + (size_t)fi * 8);
        }

    float qv[2], ov[2];
    #pragma unroll
    for (int ct = 0; ct < 2; ++ct) {
        const int c = 32 * w + 16 * ct + lr;
        qv[ct] = qbuf[b * DD + c];
        ov[ct] = omega[c];
    }
    float impv[CPB];
    if (t < ROWS) {
        #pragma unroll
        for (int c = 0; c < CPB; ++c) impv[c] = imp[b * NN + row0 + c * ROWS + t];
    }

    // ---- convert + write chunk 0 (vmcnt waits on st only; frags stay in flight) ----
    #pragma unroll
    for (int i = 0; i < 8; ++i) {
        const int idx = t + i * 256;
        const int rr  = idx >> 5;
        const int bc  = (idx & 31) * 8;
        float xs[4] = {st[i].x, st[i].y, st[i].z, st[i].w};
        unsigned short hs[4], ls[4];
        #pragma unroll
        for (int j = 0; j < 4; ++j) {
            hs[j] = f2bf_rtne(xs[j]);
            ls[j] = f2bf_rtne(xs[j] - bf2f(hs[j]));
        }
        uint2 ph, pl;
        ph.x = (unsigned)hs[0] | ((unsigned)hs[1] << 16);
        ph.y = (unsigned)hs[2] | ((unsigned)hs[3] << 16);
        pl.x = (unsigned)ls[0] | ((unsigned)ls[1] << 16);
        pl.y = (unsigned)ls[2] | ((unsigned)ls[3] << 16);
        const int off = rr * 256 + (bc ^ ((rr & 7) << 4));
        *reinterpret_cast<uint2*>(reinterpret_cast<char*>(Ehi) + off) = ph;
        *reinterpret_cast<uint2*>(reinterpret_cast<char*>(Elo) + off) = pl;
    }
    // ---- issue chunk-1 loads; they stream during chunk-0 compute ----
    #pragma unroll
    for (int i = 0; i < 8; ++i) st[i] = ejp[2048 + t + i * 256];

    ldsbar();   // E(0) published; chunk-1 loads remain in flight

    float sacc = 0.f, den_local = 0.f;
    const int rq = t >> 6;       // rowquarter for colsum (== wave id)
    const int cp = t & 63;       // column pair

    #pragma unroll
    for (int c = 0; c < CPB; ++c) {
        // ---- MFMA K-GEMM + sigma partials ----
        #pragma unroll 1
        for (int rt = 0; rt < 4; ++rt) {
            f32x4 a0 = {0.f, 0.f, 0.f, 0.f};
            f32x4 a1 = {0.f, 0.f, 0.f, 0.f};
            const int arow  = rt * 16 + lr;
            const int rbase = arow * 256;
            const int rsw   = (lr & 7) << 4;
            #pragma unroll
            for (int ks = 0; ks < 4; ++ks) {
                const int off = rbase + ((ks * 64 + lg * 16) ^ rsw);
                short8 ah = *reinterpret_cast<const short8*>(
                    reinterpret_cast<const char*>(Ehi) + off);
                short8 al = *reinterpret_cast<const short8*>(
                    reinterpret_cast<const char*>(Elo) + off);
                a0 = __builtin_amdgcn_mfma_f32_16x16x32_bf16(ah, Bh[0][ks], a0, 0, 0, 0);
                a1 = __builtin_amdgcn_mfma_f32_16x16x32_bf16(ah, Bh[1][ks], a1, 0, 0, 0);
                a0 = __builtin_amdgcn_mfma_f32_16x16x32_bf16(ah, Bl[0][ks], a0, 0, 0, 0);
                a1 = __builtin_amdgcn_mfma_f32_16x16x32_bf16(ah, Bl[1][ks], a1, 0, 0, 0);
                a0 = __builtin_amdgcn_mfma_f32_16x16x32_bf16(al, Bh[0][ks], a0, 0, 0, 0);
                a1 = __builtin_amdgcn_mfma_f32_16x16x32_bf16(al, Bh[1][ks], a1, 0, 0, 0);
            }
            float sp[4];
            #pragma unroll
            for (int i = 0; i < 4; ++i) {
                float x0 = qv[0] + a0[i];
                float x1 = qv[1] + a1[i];
                sp[i] = fmaf(ov[0], tanh_fast(x0), ov[1] * tanh_fast(x1));
            }
            #pragma unroll
            for (int m = 1; m < 16; m <<= 1) {
                #pragma unroll
                for (int i = 0; i < 4; ++i) sp[i] += __shfl_xor(sp[i], m);
            }
            if (lr == 0) {
                #pragma unroll
                for (int i = 0; i < 4; ++i) sig[rt * 16 + 4 * lg + i][w] = sp[i];
            }
        }
        ldsbar();   // sig ready; MFMA E-reads done

        // ---- exp + weights + denominator (wave 0) ----
        if (t < ROWS) {
            float sg = sig[t][0] + sig[t][1] + sig[t][2] + sig[t][3];
            float es = __expf(sg);
            wrow[t]  = es * impv[c];
            float ds = es;
            #pragma unroll
            for (int m = 1; m < 64; m <<= 1) ds += __shfl_xor(ds, m);
            if (t == 0) den_local += ds;
        }
        ldsbar();   // wrow ready

        // ---- weighted column sum (b32 reads, 4 rowquarters) ----
        {
            float a0 = 0.f, a1 = 0.f;
            #pragma unroll
            for (int j = 0; j < 16; ++j) {
                const int rr  = rq * 16 + j;
                const int off = rr * 256 + ((4 * cp) ^ ((rr & 7) << 4));
                const unsigned hbits = *reinterpret_cast<const unsigned*>(
                    reinterpret_cast<const char*>(Ehi) + off);
                const unsigned lbits = *reinterpret_cast<const unsigned*>(
                    reinterpret_cast<const char*>(Elo) + off);
                const float wv = wrow[rr];
                float v0 = bf2f((unsigned short)hbits) + bf2f((unsigned short)lbits);
                float v1 = bf2f((unsigned short)(hbits >> 16)) + bf2f((unsigned short)(lbits >> 16));
                a0 = fmaf(wv, v0, a0);
                a1 = fmaf(wv, v1, a1);
            }
            scolq[rq][2 * cp]     = a0;
            scolq[rq][2 * cp + 1] = a1;
        }
        ldsbar();   // scolq ready; all E reads complete

        if (t < DD) sacc += scolq[0][t] + scolq[1][t] + scolq[2][t] + scolq[3][t];

        if (c + 1 < CPB) {
            // ---- convert + write chunk c+1 (st loads have been streaming) ----
            #pragma unroll
            for (int i = 0; i < 8; ++i) {
                const int idx = t + i * 256;
                const int rr  = idx >> 5;
                const int bc  = (idx & 31) * 8;
                float xs[4] = {st[i].x, st[i].y, st[i].z, st[i].w};
                unsigned short hs[4], ls[4];
                #pragma unroll
                for (int j = 0; j < 4; ++j) {
                    hs[j] = f2bf_rtne(xs[j]);
                    ls[j] = f2bf_rtne(xs[j] - bf2f(hs[j]));
                }
                uint2 ph, pl;
                ph.x = (unsigned)hs[0] | ((unsigned)hs[1] << 16);
                ph.y = (unsigned)hs[2] | ((unsigned)hs[3] << 16);
                pl.x = (unsigned)ls[0] | ((unsigned)ls[1] << 16);
                pl.y = (unsigned)ls[2] | ((unsigned)ls[3] << 16);
                const int off = rr * 256 + (bc ^ ((rr & 7) << 4));
                *reinterpret_cast<uint2*>(reinterpret_cast<char*>(Ehi) + off) = ph;
                *reinterpret_cast<uint2*>(reinterpret_cast<char*>(Elo) + off) = pl;
            }
            ldsbar();   // E(c+1) published
        }
    }

    if (t < DD) atomicAdd(&sprime[b * DD + t], sacc);
    if (t == 0) atomicAdd(&denom[b], den_local);
}

// ---- fused epilogue: A_l = (s'/denom) @ Wv.T ; outputs 0,2 ; A_lk = R * A_l ----
__global__ __launch_bounds__(256) void aegis_epi(
    const float* __restrict__ sprime, const float* __restrict__ denomv,
    const float* __restrict__ Wv, const float* __restrict__ R,
    float* __restrict__ out)
{
    __shared__ float sn[DD];
    __shared__ float alred[DD][2];
    __shared__ float al[DD];
    const int t = threadIdx.x, b = blockIdx.x;

    if (t < DD) sn[t] = sprime[b * DD + t] / (denomv[b] + 1e-9f);
    __syncthreads();
    {
        const int l = t >> 1, h = t & 1;
        const float4* wr = reinterpret_cast<const float4*>(Wv + l * DD + h * 64);
        const float4* sv = reinterpret_cast<const float4*>(sn + h * 64);
        float acc = 0.f;
        #pragma unroll 8
        for (int i = 0; i < 16; ++i) {
            float4 w = wr[i], e = sv[i];
            acc = fmaf(w.x, e.x, acc); acc = fmaf(w.y, e.y, acc);
            acc = fmaf(w.z, e.z, acc); acc = fmaf(w.w, e.w, acc);
        }
        alred[l][h] = acc;
    }
    __syncthreads();
    if (t < DD) {
        float v = alred[t][0] + alred[t][1];
        al[t] = v;
        out[b * DD + t] = v;                       // A_l
        out[8192 + 1048576 + b * DD + t] = v;      // A_l (output 2)
    }
    __syncthreads();
    float4* dst = reinterpret_cast<float4*>(out + 8192 + (size_t)b * DD * DD);
    const float4* rsrc = reinterpret_cast<const float4*>(R);
    #pragma unroll
    for (int i = 0; i < 16; ++i) {
        const int idx = t + i * 256;
        float4 r = rsrc[idx];
        const int k0 = (idx & 31) * 4;
        float4 o;
        o.x = r.x * al[k0];     o.y = r.y * al[k0 + 1];
        o.z = r.z * al[k0 + 2]; o.w = r.w * al[k0 + 3];
        dst[idx] = o;
    }
}

extern "C" void kernel_launch(void* const* d_in, const int* in_sizes, int n_in,
                              void* d_out, int out_size, void* d_ws, size_t ws_size,
                              hipStream_t stream) {
    const float* e_i = (const float*)d_in[0];
    const float* e_j = (const float*)d_in[1];
    const float* imp = (const float*)d_in[2];
    const float* R   = (const float*)d_in[3];
    const float* Wq  = (const float*)d_in[4];
    const float* Wk  = (const float*)d_in[5];
    const float* Wv  = (const float*)d_in[6];
    const float* om  = (const float*)d_in[7];

    float* out    = (float*)d_out;
    float* sprime = (float*)d_ws;                        // 8192 f32
    float* denom  = (float*)((char*)d_ws + 32768);       // 64 f32

    // scratch hosted in the A_lk output region (rewritten by epi afterwards):
    float* qbuf = out + 8192;                            // 8192 f32
    unsigned short* Bhig = (unsigned short*)(out + 8192 + 8192);   // 16384 shorts
    unsigned short* Blog = Bhig + 16384;                 // 16384 shorts

    aegis_prep<<<dim3(72), dim3(256), 0, stream>>>(
        e_i, Wq, Wk, qbuf, Bhig, Blog, sprime, denom);
    aegis_main<<<dim3(BB * 16), dim3(256), 0, stream>>>(
        e_j, imp, om, qbuf, Bhig, Blog, sprime, denom);
    aegis_epi<<<dim3(BB), dim3(256), 0, stream>>>(sprime, denom, Wv, R, out);
}

// Round 9
// 133.894 us; speedup vs baseline: 1.1904x; 1.1452x over previous
//
#include <hip/hip_runtime.h>
#include <stdint.h>

#define BB 64
#define NN 2048
#define DD 128
#define ROWS 64           // neighbor rows per block; grid = 64*32 = 2048

typedef __attribute__((ext_vector_type(8))) short short8;
typedef __attribute__((ext_vector_type(4))) float f32x4;

__device__ __forceinline__ unsigned short f2bf_rtne(float x) {
    union { float f; unsigned int u; } v; v.f = x;
    unsigned int r = v.u + 0x7fffu + ((v.u >> 16) & 1u);
    return (unsigned short)(r >> 16);
}
__device__ __forceinline__ float bf2f(unsigned short h) {
    union { unsigned int u; float f; } v; v.u = ((unsigned int)h) << 16;
    return v.f;
}
__device__ __forceinline__ float tanh_fast(float x) {
    float ax = fabsf(x);
    float e  = __expf(-2.f * ax);
    float t  = (1.f - e) / (1.f + e);
    return copysignf(t, x);
}
// LDS-publish barrier: leaves global loads (vmcnt) in flight, unlike
// __syncthreads() which drains vmcnt(0).
__device__ __forceinline__ void ldsbar() {
    asm volatile("s_waitcnt lgkmcnt(0)" ::: "memory");
    __builtin_amdgcn_s_barrier();
}

// ---- prep: blocks 0..7 convert Wk -> bf16 hi/lo MFMA B-fragments;
//      blocks 8..71: q[b] = e_i[b] @ Wq.T, zero sprime/denom ----
__global__ __launch_bounds__(256) void aegis_prep(
    const float* __restrict__ e_i, const float* __restrict__ Wq,
    const float* __restrict__ Wk,
    float* __restrict__ qbuf, unsigned short* __restrict__ Bhig,
    unsigned short* __restrict__ Blog,
    float* __restrict__ sprime, float* __restrict__ denom)
{
    __shared__ float eis[DD];
    const int t = threadIdx.x, blk = blockIdx.x;
    if (blk < 8) {
        const int tid = blk * 256 + t;
        const int lr = tid & 15, lg = (tid >> 4) & 3, ks = (tid >> 6) & 3, et = tid >> 8;
        const int e = et * 16 + lr, k = ks * 32 + lg * 8;
        const float* src = Wk + e * DD + k;
        float4 x0 = *reinterpret_cast<const float4*>(src);
        float4 x1 = *reinterpret_cast<const float4*>(src + 4);
        float xs[8] = {x0.x, x0.y, x0.z, x0.w, x1.x, x1.y, x1.z, x1.w};
        short8 h, l;
        #pragma unroll
        for (int j = 0; j < 8; ++j) {
            unsigned short hb = f2bf_rtne(xs[j]);
            float rem = xs[j] - bf2f(hb);
            h[j] = (short)hb;
            l[j] = (short)f2bf_rtne(rem);
        }
        *reinterpret_cast<short8*>(Bhig + (size_t)tid * 8) = h;
        *reinterpret_cast<short8*>(Blog + (size_t)tid * 8) = l;
    } else {
        const int b = blk - 8;
        if (t < DD) eis[t] = e_i[b * DD + t];
        __syncthreads();
        if (t < DD) {
            float acc = 0.f;
            const float4* wr = reinterpret_cast<const float4*>(Wq + t * DD);
            const float4* ev = reinterpret_cast<const float4*>(eis);
            #pragma unroll 8
            for (int i = 0; i < 32; ++i) {
                float4 w = wr[i], e = ev[i];
                acc = fmaf(w.x, e.x, acc); acc = fmaf(w.y, e.y, acc);
                acc = fmaf(w.z, e.z, acc); acc = fmaf(w.w, e.w, acc);
            }
            qbuf[b * DD + t] = acc;
            sprime[b * DD + t] = 0.f;
        }
        if (t == 0) denom[b] = 0.f;
    }
}

// ---- main: one 64-row chunk per block; overlap via block-level TLP ----
__global__ __launch_bounds__(256) void aegis_main(
    const float* __restrict__ e_j, const float* __restrict__ imp,
    const float* __restrict__ omega, const float* __restrict__ qbuf,
    const unsigned short* __restrict__ Bhig, const unsigned short* __restrict__ Blog,
    float* __restrict__ sprime, float* __restrict__ denom)
{
    __shared__ unsigned short Ehi[ROWS * DD];   // byte off = rr*256 + (col_bytes ^ ((rr&7)<<4))
    __shared__ unsigned short Elo[ROWS * DD];
    __shared__ float sig[ROWS][4];
    __shared__ float wrow[ROWS];
    __shared__ float scolq[4][DD];

    const int t     = threadIdx.x;
    const int b     = blockIdx.x >> 5;
    const int chunk = blockIdx.x & 31;
    const int row0  = chunk * ROWS;
    const int lane  = t & 63;
    const int w     = t >> 6;
    const int lr    = lane & 15;
    const int lg    = lane >> 4;

    // ---- issue e_j loads first (oldest vmcnt slots -> waited on first) ----
    float4 st[8];
    const float4* ejp = reinterpret_cast<const float4*>(
        e_j + (size_t)(b * NN + row0) * DD);
    #pragma unroll
    for (int i = 0; i < 8; ++i) st[i] = ejp[t + i * 256];

    // ---- B fragments (L2-hot; counted vmcnt lets convert start before these land) ----
    short8 Bh[2][4], Bl[2][4];
    #pragma unroll
    for (int ct = 0; ct < 2; ++ct)
        #pragma unroll
        for (int ks = 0; ks < 4; ++ks) {
            const int fi = (((2 * w + ct) * 4 + ks) * 4 + lg) * 16 + lr;
            Bh[ct][ks] = *reinterpret_cast<const short8*>(Bhig + (size_t)fi * 8);
            Bl[ct][ks] = *reinterpret_cast<const short8*>(Blog + (size_t)fi * 8);
        }

    float qv[2], ov[2];
    #pragma unroll
    for (int ct = 0; ct < 2; ++ct) {
        const int c = 32 * w + 16 * ct + lr;
        qv[ct] = qbuf[b * DD + c];
        ov[ct] = omega[c];
    }
    const float impv = (t < ROWS) ? imp[b * NN + row0 + t] : 0.f;

    // ---- convert + write to LDS (short live range; no spill) ----
    #pragma unroll
    for (int i = 0; i < 8; ++i) {
        const int idx = t + i * 256;
        const int rr  = idx >> 5;
        const int bc  = (idx & 31) * 8;
        float xs[4] = {st[i].x, st[i].y, st[i].z, st[i].w};
        unsigned short hs[4], ls[4];
        #pragma unroll
        for (int j = 0; j < 4; ++j) {
            hs[j] = f2bf_rtne(xs[j]);
            ls[j] = f2bf_rtne(xs[j] - bf2f(hs[j]));
        }
        uint2 ph, pl;
        ph.x = (unsigned)hs[0] | ((unsigned)hs[1] << 16);
        ph.y = (unsigned)hs[2] | ((unsigned)hs[3] << 16);
        pl.x = (unsigned)ls[0] | ((unsigned)ls[1] << 16);
        pl.y = (unsigned)ls[2] | ((unsigned)ls[3] << 16);
        const int off = rr * 256 + (bc ^ ((rr & 7) << 4));
        *reinterpret_cast<uint2*>(reinterpret_cast<char*>(Ehi) + off) = ph;
        *reinterpret_cast<uint2*>(reinterpret_cast<char*>(Elo) + off) = pl;
    }
    ldsbar();   // E published

    // ---- MFMA K-GEMM (3-term bf16 split) + sigma partials ----
    #pragma unroll 1
    for (int rt = 0; rt < 4; ++rt) {
        f32x4 a0 = {0.f, 0.f, 0.f, 0.f};
        f32x4 a1 = {0.f, 0.f, 0.f, 0.f};
        const int rbase = (rt * 16 + lr) * 256;
        const int rsw   = (lr & 7) << 4;
        #pragma unroll
        for (int ks = 0; ks < 4; ++ks) {
            const int off = rbase + ((ks * 64 + lg * 16) ^ rsw);
            short8 ah = *reinterpret_cast<const short8*>(
                reinterpret_cast<const char*>(Ehi) + off);
            short8 al = *reinterpret_cast<const short8*>(
                reinterpret_cast<const char*>(Elo) + off);
            a0 = __builtin_amdgcn_mfma_f32_16x16x32_bf16(ah, Bh[0][ks], a0, 0, 0, 0);
            a1 = __builtin_amdgcn_mfma_f32_16x16x32_bf16(ah, Bh[1][ks], a1, 0, 0, 0);
            a0 = __builtin_amdgcn_mfma_f32_16x16x32_bf16(ah, Bl[0][ks], a0, 0, 0, 0);
            a1 = __builtin_amdgcn_mfma_f32_16x16x32_bf16(ah, Bl[1][ks], a1, 0, 0, 0);
            a0 = __builtin_amdgcn_mfma_f32_16x16x32_bf16(al, Bh[0][ks], a0, 0, 0, 0);
            a1 = __builtin_amdgcn_mfma_f32_16x16x32_bf16(al, Bh[1][ks], a1, 0, 0, 0);
        }
        float sp[4];
        #pragma unroll
        for (int i = 0; i < 4; ++i) {
            float x0 = qv[0] + a0[i];
            float x1 = qv[1] + a1[i];
            sp[i] = fmaf(ov[0], tanh_fast(x0), ov[1] * tanh_fast(x1));
        }
        #pragma unroll
        for (int m = 1; m < 16; m <<= 1) {
            #pragma unroll
            for (int i = 0; i < 4; ++i) sp[i] += __shfl_xor(sp[i], m);
        }
        if (lr == 0) {
            #pragma unroll
            for (int i = 0; i < 4; ++i) sig[rt * 16 + 4 * lg + i][w] = sp[i];
        }
    }
    ldsbar();   // sig ready

    // ---- exp + weights + denominator (wave 0) ----
    float den_local = 0.f;
    if (t < ROWS) {
        float sg = sig[t][0] + sig[t][1] + sig[t][2] + sig[t][3];
        float es = __expf(sg);
        wrow[t]  = es * impv;
        float ds = es;
        #pragma unroll
        for (int m = 1; m < 64; m <<= 1) ds += __shfl_xor(ds, m);
        den_local = ds;
    }
    ldsbar();   // wrow ready

    // ---- weighted column sum (b32 reads, 4 rowquarters) ----
    {
        const int rq = t >> 6;
        const int cp = t & 63;
        float a0 = 0.f, a1 = 0.f;
        #pragma unroll
        for (int j = 0; j < 16; ++j) {
            const int rr  = rq * 16 + j;
            const int off = rr * 256 + ((4 * cp) ^ ((rr & 7) << 4));
            const unsigned hbits = *reinterpret_cast<const unsigned*>(
                reinterpret_cast<const char*>(Ehi) + off);
            const unsigned lbits = *reinterpret_cast<const unsigned*>(
                reinterpret_cast<const char*>(Elo) + off);
            const float wv = wrow[rr];
            float v0 = bf2f((unsigned short)hbits) + bf2f((unsigned short)lbits);
            float v1 = bf2f((unsigned short)(hbits >> 16)) + bf2f((unsigned short)(lbits >> 16));
            a0 = fmaf(wv, v0, a0);
            a1 = fmaf(wv, v1, a1);
        }
        scolq[rq][2 * cp]     = a0;
        scolq[rq][2 * cp + 1] = a1;
    }
    ldsbar();   // scolq ready

    if (t < DD) {
        const float s = scolq[0][t] + scolq[1][t] + scolq[2][t] + scolq[3][t];
        atomicAdd(&sprime[b * DD + t], s);
    }
    if (t == 0) atomicAdd(&denom[b], den_local);
}

// ---- fused epilogue: A_l = (s'/denom) @ Wv.T ; outputs 0,2 ; A_lk = R * A_l ----
__global__ __launch_bounds__(256) void aegis_epi(
    const float* __restrict__ sprime, const float* __restrict__ denomv,
    const float* __restrict__ Wv, const float* __restrict__ R,
    float* __restrict__ out)
{
    __shared__ float sn[DD];
    __shared__ float alred[DD][2];
    __shared__ float al[DD];
    const int t = threadIdx.x, b = blockIdx.x;

    if (t < DD) sn[t] = sprime[b * DD + t] / (denomv[b] + 1e-9f);
    __syncthreads();
    {
        const int l = t >> 1, h = t & 1;
        const float4* wr = reinterpret_cast<const float4*>(Wv + l * DD + h * 64);
        const float4* sv = reinterpret_cast<const float4*>(sn + h * 64);
        float acc = 0.f;
        #pragma unroll 8
        for (int i = 0; i < 16; ++i) {
            float4 w = wr[i], e = sv[i];
            acc = fmaf(w.x, e.x, acc); acc = fmaf(w.y, e.y, acc);
            acc = fmaf(w.z, e.z, acc); acc = fmaf(w.w, e.w, acc);
        }
        alred[l][h] = acc;
    }
    __syncthreads();
    if (t < DD) {
        float v = alred[t][0] + alred[t][1];
        al[t] = v;
        out[b * DD + t] = v;                       // A_l
        out[8192 + 1048576 + b * DD + t] = v;      // A_l (output 2)
    }
    __syncthreads();
    float4* dst = reinterpret_cast<float4*>(out + 8192 + (size_t)b * DD * DD);
    const float4* rsrc = reinterpret_cast<const float4*>(R);
    #pragma unroll
    for (int i = 0; i < 16; ++i) {
        const int idx = t + i * 256;
        float4 r = rsrc[idx];
        const int k0 = (idx & 31) * 4;
        float4 o;
        o.x = r.x * al[k0];     o.y = r.y * al[k0 + 1];
        o.z = r.z * al[k0 + 2]; o.w = r.w * al[k0 + 3];
        dst[idx] = o;
    }
}

extern "C" void kernel_launch(void* const* d_in, const int* in_sizes, int n_in,
                              void* d_out, int out_size, void* d_ws, size_t ws_size,
                              hipStream_t stream) {
    const float* e_i = (const float*)d_in[0];
    const float* e_j = (const float*)d_in[1];
    const float* imp = (const float*)d_in[2];
    const float* R   = (const float*)d_in[3];
    const float* Wq  = (const float*)d_in[4];
    const float* Wk  = (const float*)d_in[5];
    const float* Wv  = (const float*)d_in[6];
    const float* om  = (const float*)d_in[7];

    float* out    = (float*)d_out;
    float* sprime = (float*)d_ws;                        // 8192 f32
    float* denom  = (float*)((char*)d_ws + 32768);       // 64 f32

    // scratch hosted in the A_lk output region (rewritten by epi afterwards):
    float* qbuf = out + 8192;                            // 8192 f32
    unsigned short* Bhig = (unsigned short*)(out + 8192 + 8192);   // 16384 shorts
    unsigned short* Blog = Bhig + 16384;                 // 16384 shorts

    aegis_prep<<<dim3(72), dim3(256), 0, stream>>>(
        e_i, Wq, Wk, qbuf, Bhig, Blog, sprime, denom);
    aegis_main<<<dim3(BB * 32), dim3(256), 0, stream>>>(
        e_j, imp, om, qbuf, Bhig, Blog, sprime, denom);
    aegis_epi<<<dim3(BB), dim3(256), 0, stream>>>(sprime, denom, Wv, R, out);
}